// Round 8
// baseline (277.764 us; speedup 1.0000x reference)
//
#include <hip/hip_runtime.h>
#include <math.h>

#define DD 128
#define CF 48          // bucket capacity/row: conv2 + conv0 (Poisson λ=12)
#define C1 16          // bucket capacity/row: conv1 compact (pooled-src only, λ≈3)
#define OVF_CAP 4096   // overflow side-list capacity (expected use: 0)

static inline int cdiv(long a, long b){ return (int)((a + b - 1) / b); }

typedef __attribute__((ext_vector_type(4))) float f32x4;
typedef __attribute__((ext_vector_type(8))) short bf16x8;
typedef __attribute__((ext_vector_type(4))) short sh4;

__device__ __forceinline__ unsigned short bf16_rn(float f){
  unsigned u = __float_as_uint(f);
  u += 0x7fffu + ((u >> 16) & 1u);
  return (unsigned short)(u >> 16);
}

// ---------- pass 1: degree count + rank capture, 4 edges/thread (4x atomic MLP) ----------
// Atomics gate only coalesced rank stores; scattered placement happens in pass 2.
__global__ void k_count(const int* __restrict__ dst_f, int nF4, int Ef,
                        int* __restrict__ cnt_f, int* __restrict__ rank_f,
                        const int* __restrict__ dst_p, int nP4, int Ep,
                        int* __restrict__ cnt_p, int* __restrict__ rank_p,
                        const int* __restrict__ unpool, int* __restrict__ invm, int npool){
  int t = blockIdx.x * blockDim.x + threadIdx.x;
  if (t < nF4){
    int e = t * 4;
    int4 d = *(const int4*)(dst_f + e);
    int r0 = atomicAdd(&cnt_f[d.x], 1);
    int r1 = atomicAdd(&cnt_f[d.y], 1);
    int r2 = atomicAdd(&cnt_f[d.z], 1);
    int r3 = atomicAdd(&cnt_f[d.w], 1);
    *(int4*)(rank_f + e) = make_int4(r0, r1, r2, r3);
    return;
  }
  t -= nF4;
  int remF = Ef - nF4 * 4;
  if (t < remF){ int e = nF4 * 4 + t; rank_f[e] = atomicAdd(&cnt_f[dst_f[e]], 1); return; }
  t -= remF;
  if (t < nP4){
    int e = t * 4;
    int4 d = *(const int4*)(dst_p + e);
    int r0 = atomicAdd(&cnt_p[d.x], 1);
    int r1 = atomicAdd(&cnt_p[d.y], 1);
    int r2 = atomicAdd(&cnt_p[d.z], 1);
    int r3 = atomicAdd(&cnt_p[d.w], 1);
    *(int4*)(rank_p + e) = make_int4(r0, r1, r2, r3);
    return;
  }
  t -= nP4;
  int remP = Ep - nP4 * 4;
  if (t < remP){ int e = nP4 * 4 + t; rank_p[e] = atomicAdd(&cnt_p[dst_p[e]], 1); return; }
  t -= remP;
  if (t < npool) invm[unpool[t]] = t + 1;   // 0 = not pooled, else pr+1
}

// ---------- pass 2: bucket fill, 4 edges/thread, raw-id 4B records ----------
// No cnt[] gathers here (weights derived in aggs); stores depend only on coalesced loads.
__global__ void k_fill(const int* __restrict__ src_f, const int* __restrict__ dst_f,
                       int nF4, int Ef,
                       const int* __restrict__ rank_f, const int* __restrict__ invm,
                       unsigned* __restrict__ ew2, int4* __restrict__ ovf2, int* __restrict__ novf2,
                       int* __restrict__ rk1, unsigned* __restrict__ ew1,
                       int4* __restrict__ ovf1, int* __restrict__ novf1,
                       const int* __restrict__ src_p, const int* __restrict__ dst_p,
                       int nP4, int Ep,
                       const int* __restrict__ rank_p,
                       unsigned* __restrict__ ew0, int4* __restrict__ ovf0, int* __restrict__ novf0){
  int t = blockIdx.x * blockDim.x + threadIdx.x;
  if (t < nF4){
    int e = t * 4;
    int4 s4 = *(const int4*)(src_f + e);
    int4 d4 = *(const int4*)(dst_f + e);
    int4 r4 = *(const int4*)(rank_f + e);
    int sa[4] = {s4.x, s4.y, s4.z, s4.w};
    int da[4] = {d4.x, d4.y, d4.z, d4.w};
    int ra[4] = {r4.x, r4.y, r4.z, r4.w};
    int pa[4];
    #pragma unroll
    for (int i = 0; i < 4; i++) pa[i] = invm[sa[i]];
    #pragma unroll
    for (int i = 0; i < 4; i++){
      if (ra[i] < CF) ew2[(long)da[i] * CF + ra[i]] = (unsigned)sa[i];
      else { int o = atomicAdd(novf2, 1); if (o < OVF_CAP) ovf2[o] = make_int4(sa[i], 0, da[i], 0); }
    }
    #pragma unroll
    for (int i = 0; i < 4; i++){
      if (pa[i] > 0){
        int pr = pa[i] - 1;
        int r1 = atomicAdd(&rk1[da[i]], 1);
        if (r1 < C1) ew1[(long)da[i] * C1 + r1] = (unsigned)pr;
        else { int o = atomicAdd(novf1, 1); if (o < OVF_CAP) ovf1[o] = make_int4(pr, sa[i], da[i], 0); }
      }
    }
    return;
  }
  t -= nF4;
  int remF = Ef - nF4 * 4;
  if (t < remF){
    int e = nF4 * 4 + t;
    int s = src_f[e], d = dst_f[e], r = rank_f[e];
    if (r < CF) ew2[(long)d * CF + r] = (unsigned)s;
    else { int o = atomicAdd(novf2, 1); if (o < OVF_CAP) ovf2[o] = make_int4(s, 0, d, 0); }
    int pv = invm[s];
    if (pv > 0){
      int pr = pv - 1;
      int r1 = atomicAdd(&rk1[d], 1);
      if (r1 < C1) ew1[(long)d * C1 + r1] = (unsigned)pr;
      else { int o = atomicAdd(novf1, 1); if (o < OVF_CAP) ovf1[o] = make_int4(pr, s, d, 0); }
    }
    return;
  }
  t -= remF;
  if (t < nP4){
    int e = t * 4;
    int4 s4 = *(const int4*)(src_p + e);
    int4 d4 = *(const int4*)(dst_p + e);
    int4 r4 = *(const int4*)(rank_p + e);
    int sa[4] = {s4.x, s4.y, s4.z, s4.w};
    int da[4] = {d4.x, d4.y, d4.z, d4.w};
    int ra[4] = {r4.x, r4.y, r4.z, r4.w};
    #pragma unroll
    for (int i = 0; i < 4; i++){
      if (ra[i] < CF) ew0[(long)da[i] * CF + ra[i]] = (unsigned)sa[i];
      else { int o = atomicAdd(novf0, 1); if (o < OVF_CAP) ovf0[o] = make_int4(sa[i], 0, da[i], 0); }
    }
    return;
  }
  t -= nP4;
  int remP = Ep - nP4 * 4;
  if (t < remP){
    int e = nP4 * 4 + t;
    int s = src_p[e], d = dst_p[e], r = rank_p[e];
    if (r < CF) ew0[(long)d * CF + r] = (unsigned)s;
    else { int o = atomicAdd(novf0, 1); if (o < OVF_CAP) ovf0[o] = make_int4(s, 0, d, 0); }
  }
}

// ---------- MFMA GEMM: xw = A @ W, hi/lo bf16 split (fp32-grade accuracy)
// AMODE 0: A is fp32, split in-kernel. AMODE 1: A is packed ushort2{hi,lo} (uint per elem).
// 128 rows/block, 4 waves x 32 rows. W transposed+swizzled in LDS (hi/lo bf16, 64KB).
// D-layout (HW-verified): row = (lane>>4)*4 + reg, col = lane&15.
template <int AMODE, bool BF16OUT>
__global__ __launch_bounds__(256, 2) void k_gemm_mfma(const void* __restrict__ Ap,
                                                      const float* __restrict__ W,
                                                      void* __restrict__ Cout, int n){
  __shared__ unsigned short Wl[2][16384];   // [hi/lo][col-major bf16, XOR-swizzled 16B slots]
  const int t    = threadIdx.x;
  const int lane = t & 63;
  const int wv   = t >> 6;    // wave 0..3
  const int g    = lane >> 4; // k-group 0..3
  const int r    = lane & 15; // row-within-frag (A) / col-within-frag (B,D)

  // ---- stage W: read row-major fp32 coalesced, write transposed bf16 hi/lo ----
  // swizzle: byte = col*256 + ((k>>3) ^ (col&15))*16 + (k&7)*2
  #pragma unroll
  for (int i = 0; i < 4; i++){
    int item = t + i * 256;
    int kq = item >> 5;            // k = kq*4 + kk
    int c4 = item & 31;            // col = c4*4 + m
    const float* Wp = W + (long)kq * 512 + c4 * 4;
    float4 ww[4];
    #pragma unroll
    for (int kk = 0; kk < 4; kk++) ww[kk] = *(const float4*)(Wp + kk * 128);
    #pragma unroll
    for (int m = 0; m < 4; m++){
      int c = c4 * 4 + m;
      int boff = c * 256 + (((kq >> 1) ^ (c & 15)) * 16) + (kq & 1) * 8;
      sh4 hq, lq;
      #pragma unroll
      for (int kk = 0; kk < 4; kk++){
        float f = ((const float*)&ww[kk])[m];
        unsigned short hh = bf16_rn(f);
        float hf = __uint_as_float((unsigned)hh << 16);
        hq[kk] = (short)hh;
        lq[kk] = (short)bf16_rn(f - hf);
      }
      *(sh4*)((char*)(&Wl[0][0]) + boff) = hq;
      *(sh4*)((char*)(&Wl[1][0]) + boff) = lq;
    }
  }
  __syncthreads();

  const int rb = blockIdx.x * 128 + wv * 32;
  const int r0 = rb + r, r1 = rb + 16 + r;
  const bool v0 = r0 < n, v1 = r1 < n;

  f32x4 acc[2][8];
  #pragma unroll
  for (int i = 0; i < 2; i++)
    #pragma unroll
    for (int j = 0; j < 8; j++){ f32x4 z = {0.f,0.f,0.f,0.f}; acc[i][j] = z; }

  #pragma unroll
  for (int ks = 0; ks < 4; ks++){
    bf16x8 ah0, al0, ah1, al1;
    if (AMODE == 0){
      const float* pa0 = (const float*)Ap + (long)r0 * DD + g * 8;
      const float* pa1 = (const float*)Ap + (long)r1 * DD + g * 8;
      const float4 z4 = make_float4(0.f,0.f,0.f,0.f);
      float4 a00 = v0 ? *(const float4*)(pa0 + ks * 32)     : z4;
      float4 a01 = v0 ? *(const float4*)(pa0 + ks * 32 + 4) : z4;
      float4 a10 = v1 ? *(const float4*)(pa1 + ks * 32)     : z4;
      float4 a11 = v1 ? *(const float4*)(pa1 + ks * 32 + 4) : z4;
      float f0[8] = {a00.x,a00.y,a00.z,a00.w,a01.x,a01.y,a01.z,a01.w};
      float f1[8] = {a10.x,a10.y,a10.z,a10.w,a11.x,a11.y,a11.z,a11.w};
      #pragma unroll
      for (int i = 0; i < 8; i++){
        unsigned short hh = bf16_rn(f0[i]);
        ah0[i] = (short)hh;
        al0[i] = (short)bf16_rn(f0[i] - __uint_as_float((unsigned)hh << 16));
        unsigned short h1 = bf16_rn(f1[i]);
        ah1[i] = (short)h1;
        al1[i] = (short)bf16_rn(f1[i] - __uint_as_float((unsigned)h1 << 16));
      }
    } else {
      const unsigned* qa0 = (const unsigned*)Ap + (long)r0 * DD + g * 8;
      const unsigned* qa1 = (const unsigned*)Ap + (long)r1 * DD + g * 8;
      const uint4 z4 = make_uint4(0,0,0,0);
      uint4 u00 = v0 ? *(const uint4*)(qa0 + ks * 32)     : z4;
      uint4 u01 = v0 ? *(const uint4*)(qa0 + ks * 32 + 4) : z4;
      uint4 u10 = v1 ? *(const uint4*)(qa1 + ks * 32)     : z4;
      uint4 u11 = v1 ? *(const uint4*)(qa1 + ks * 32 + 4) : z4;
      unsigned uu0[8] = {u00.x,u00.y,u00.z,u00.w,u01.x,u01.y,u01.z,u01.w};
      unsigned uu1[8] = {u10.x,u10.y,u10.z,u10.w,u11.x,u11.y,u11.z,u11.w};
      #pragma unroll
      for (int i = 0; i < 8; i++){
        ah0[i] = (short)(uu0[i] & 0xffffu); al0[i] = (short)(uu0[i] >> 16);
        ah1[i] = (short)(uu1[i] & 0xffffu); al1[i] = (short)(uu1[i] >> 16);
      }
    }
    const int sb = ks * 4 + g;
    #pragma unroll
    for (int cf = 0; cf < 8; cf++){
      const int boff = (cf * 16 + r) * 256 + ((sb ^ r) * 16);
      bf16x8 wh = *(const bf16x8*)((const char*)(&Wl[0][0]) + boff);
      bf16x8 wl = *(const bf16x8*)((const char*)(&Wl[1][0]) + boff);
      acc[0][cf] = __builtin_amdgcn_mfma_f32_16x16x32_bf16(ah0, wh, acc[0][cf], 0, 0, 0);
      acc[1][cf] = __builtin_amdgcn_mfma_f32_16x16x32_bf16(ah1, wh, acc[1][cf], 0, 0, 0);
      acc[0][cf] = __builtin_amdgcn_mfma_f32_16x16x32_bf16(al0, wh, acc[0][cf], 0, 0, 0);
      acc[1][cf] = __builtin_amdgcn_mfma_f32_16x16x32_bf16(al1, wh, acc[1][cf], 0, 0, 0);
      acc[0][cf] = __builtin_amdgcn_mfma_f32_16x16x32_bf16(ah0, wl, acc[0][cf], 0, 0, 0);
      acc[1][cf] = __builtin_amdgcn_mfma_f32_16x16x32_bf16(ah1, wl, acc[1][cf], 0, 0, 0);
    }
  }

  #pragma unroll
  for (int rf = 0; rf < 2; rf++){
    #pragma unroll
    for (int cf = 0; cf < 8; cf++){
      #pragma unroll
      for (int e = 0; e < 4; e++){
        int row = rb + rf * 16 + g * 4 + e;
        if (row < n){
          float v = acc[rf][cf][e];
          if (BF16OUT)
            ((unsigned short*)Cout)[(long)row * DD + cf * 16 + r] = bf16_rn(v);
          else
            ((float*)Cout)[(long)row * DD + cf * 16 + r] = v;
        }
      }
    }
  }
}

// ---------- conv0 agg: pool graph, fp32 payload, raw-id records, weights from cnt ----------
__global__ __launch_bounds__(256) void k_agg0(const float* __restrict__ xw,
    const int* __restrict__ cnt, const unsigned* __restrict__ ew,
    const int4* __restrict__ ovf, const int* __restrict__ novf,
    const float* __restrict__ b, unsigned* __restrict__ outp, int n){
  int row = __builtin_amdgcn_readfirstlane(blockIdx.x * 4 + (threadIdx.x >> 6));
  if (row >= n) return;
  int c = (threadIdx.x & 63) * 2;
  int deg = __builtin_amdgcn_readfirstlane(cnt[row]);
  int m = deg < CF ? deg : CF;
  long base = (long)row * CF;
  float ax[8], ay[8];
  #pragma unroll
  for (int i = 0; i < 8; i++){ ax[i] = 0.f; ay[i] = 0.f; }
  for (int j0 = 0; j0 < m; j0 += 16){
    uint4 q0 = *(const uint4*)(ew + base + j0);
    uint4 q1 = *(const uint4*)(ew + base + j0 + 4);
    uint4 q2 = *(const uint4*)(ew + base + j0 + 8);
    uint4 q3 = *(const uint4*)(ew + base + j0 + 12);
    unsigned ua[16] = {q0.x,q0.y,q0.z,q0.w, q1.x,q1.y,q1.z,q1.w,
                       q2.x,q2.y,q2.z,q2.w, q3.x,q3.y,q3.z,q3.w};
    float2 v[16]; float w[16];
    #pragma unroll
    for (int i = 0; i < 16; i++){
      bool val = (j0 + i) < m;
      int s = val ? (int)ua[i] : row;              // invalid -> own row (hot line, w=0)
      w[i] = val ? rsqrtf((float)cnt[s] + 1.f) : 0.f;
      v[i] = *(const float2*)(xw + (long)s * DD + c);
    }
    #pragma unroll
    for (int i = 0; i < 16; i++){
      ax[i & 7] += v[i].x * w[i];
      ay[i & 7] += v[i].y * w[i];
    }
  }
  int no = __builtin_amdgcn_readfirstlane(novf[0]);
  if (no > 0){
    no = no < OVF_CAP ? no : OVF_CAP;
    for (int k = 0; k < no; k++){
      int4 od = ovf[k];
      if (od.z == row){
        float w = rsqrtf((float)cnt[od.x] + 1.f);
        float2 v = *(const float2*)(xw + (long)od.x * DD + c);
        ax[0] += v.x * w; ay[0] += v.y * w;
      }
    }
  }
  float sax = ((ax[0]+ax[1])+(ax[2]+ax[3])) + ((ax[4]+ax[5])+(ax[6]+ax[7]));
  float say = ((ay[0]+ay[1])+(ay[2]+ay[3])) + ((ay[4]+ay[5])+(ay[6]+ay[7]));
  float dd = rsqrtf((float)deg + 1.f);
  float2 sv = *(const float2*)(xw + (long)row * DD + c);
  float2 bb = *(const float2*)(b + c);
  float vx = sax * dd + sv.x * dd * dd + bb.x;
  float vy = say * dd + sv.y * dd * dd + bb.y;
  vx = vx > 0.f ? vx : expm1f(vx);
  vy = vy > 0.f ? vy : expm1f(vy);
  unsigned short hx = bf16_rn(vx);
  unsigned short lx = bf16_rn(vx - __uint_as_float((unsigned)hx << 16));
  unsigned short hy = bf16_rn(vy);
  unsigned short ly = bf16_rn(vy - __uint_as_float((unsigned)hy << 16));
  *(uint2*)(outp + (long)row * DD + c) =
      make_uint2((unsigned)hx | ((unsigned)lx << 16), (unsigned)hy | ((unsigned)ly << 16));
}

// ---------- conv1 agg: compact pooled-src pr-records; s via unpool; weights from cnt_f ----------
__global__ __launch_bounds__(256) void k_agg1(const unsigned short* __restrict__ hwb,
    const int* __restrict__ invm, const int* __restrict__ cnt_f,
    const int* __restrict__ rk1, const unsigned* __restrict__ ew,
    const int* __restrict__ unpool,
    const int4* __restrict__ ovf, const int* __restrict__ novf,
    const float* __restrict__ b, unsigned* __restrict__ outp, int n){
  int row = __builtin_amdgcn_readfirstlane(blockIdx.x * 4 + (threadIdx.x >> 6));
  if (row >= n) return;
  int c = (threadIdx.x & 63) * 2;
  int m1 = __builtin_amdgcn_readfirstlane(rk1[row]);
  if (m1 > C1) m1 = C1;
  int deg = __builtin_amdgcn_readfirstlane(cnt_f[row]);
  long base = (long)row * C1;
  int pv = __builtin_amdgcn_readfirstlane(invm[row]);
  float ax[8], ay[8];
  #pragma unroll
  for (int i = 0; i < 8; i++){ ax[i] = 0.f; ay[i] = 0.f; }
  if (m1 > 0){
    uint4 q0 = *(const uint4*)(ew + base);
    uint4 q1 = *(const uint4*)(ew + base + 4);
    uint4 q2 = *(const uint4*)(ew + base + 8);
    uint4 q3 = *(const uint4*)(ew + base + 12);
    unsigned ua[16] = {q0.x,q0.y,q0.z,q0.w, q1.x,q1.y,q1.z,q1.w,
                       q2.x,q2.y,q2.z,q2.w, q3.x,q3.y,q3.z,q3.w};
    unsigned v[16]; float w[16];
    #pragma unroll
    for (int i = 0; i < 16; i++){
      bool val = i < m1;
      int pr = val ? (int)ua[i] : 0;               // row 0 of hwb: valid data, w=0
      int s  = val ? unpool[pr] : 0;
      w[i] = val ? rsqrtf((float)cnt_f[s] + 1.f) : 0.f;
      v[i] = *(const unsigned*)(hwb + (long)pr * DD + c);
    }
    #pragma unroll
    for (int i = 0; i < 16; i++){
      ax[i & 7] += __uint_as_float(v[i] << 16) * w[i];
      ay[i & 7] += __uint_as_float(v[i] & 0xffff0000u) * w[i];
    }
  }
  int no = __builtin_amdgcn_readfirstlane(novf[0]);
  if (no > 0){
    no = no < OVF_CAP ? no : OVF_CAP;
    for (int k = 0; k < no; k++){
      int4 od = ovf[k];   // (pr, s, d, 0)
      if (od.z == row){
        float w = rsqrtf((float)cnt_f[od.y] + 1.f);
        unsigned v = *(const unsigned*)(hwb + (long)od.x * DD + c);
        ax[0] += __uint_as_float(v << 16) * w;
        ay[0] += __uint_as_float(v & 0xffff0000u) * w;
      }
    }
  }
  float sax = ((ax[0]+ax[1])+(ax[2]+ax[3])) + ((ax[4]+ax[5])+(ax[6]+ax[7]));
  float say = ((ay[0]+ay[1])+(ay[2]+ay[3])) + ((ay[4]+ay[5])+(ay[6]+ay[7]));
  float dd = rsqrtf((float)deg + 1.f);
  float sx = 0.f, sy = 0.f;
  if (pv > 0){
    unsigned sv = *(const unsigned*)(hwb + (long)(pv - 1) * DD + c);
    sx = __uint_as_float(sv << 16); sy = __uint_as_float(sv & 0xffff0000u);
  }
  float2 bb = *(const float2*)(b + c);
  float vx = sax * dd + sx * dd * dd + bb.x;
  float vy = say * dd + sy * dd * dd + bb.y;
  vx = vx > 0.f ? vx : expm1f(vx);
  vy = vy > 0.f ? vy : expm1f(vy);
  unsigned short hx = bf16_rn(vx);
  unsigned short lx = bf16_rn(vx - __uint_as_float((unsigned)hx << 16));
  unsigned short hy = bf16_rn(vy);
  unsigned short ly = bf16_rn(vy - __uint_as_float((unsigned)hy << 16));
  *(uint2*)(outp + (long)row * DD + c) =
      make_uint2((unsigned)hx | ((unsigned)lx << 16), (unsigned)hy | ((unsigned)ly << 16));
}

// ---------- conv2 agg: full graph, raw-id records, weights from cnt, fp32 out ----------
__global__ __launch_bounds__(256) void k_agg2(const unsigned short* __restrict__ xwb,
    const int* __restrict__ cnt, const unsigned* __restrict__ ew,
    const int4* __restrict__ ovf, const int* __restrict__ novf,
    const float* __restrict__ b, float* __restrict__ out, int n){
  int row = __builtin_amdgcn_readfirstlane(blockIdx.x * 4 + (threadIdx.x >> 6));
  if (row >= n) return;
  int c = (threadIdx.x & 63) * 2;
  int deg = __builtin_amdgcn_readfirstlane(cnt[row]);
  int m = deg < CF ? deg : CF;
  long base = (long)row * CF;
  float ax[8], ay[8];
  #pragma unroll
  for (int i = 0; i < 8; i++){ ax[i] = 0.f; ay[i] = 0.f; }
  for (int j0 = 0; j0 < m; j0 += 16){
    uint4 q0 = *(const uint4*)(ew + base + j0);
    uint4 q1 = *(const uint4*)(ew + base + j0 + 4);
    uint4 q2 = *(const uint4*)(ew + base + j0 + 8);
    uint4 q3 = *(const uint4*)(ew + base + j0 + 12);
    unsigned ua[16] = {q0.x,q0.y,q0.z,q0.w, q1.x,q1.y,q1.z,q1.w,
                       q2.x,q2.y,q2.z,q2.w, q3.x,q3.y,q3.z,q3.w};
    unsigned v[16]; float w[16];
    #pragma unroll
    for (int i = 0; i < 16; i++){
      bool val = (j0 + i) < m;
      int s = val ? (int)ua[i] : row;              // invalid -> own row (hot line, w=0)
      w[i] = val ? rsqrtf((float)cnt[s] + 1.f) : 0.f;
      v[i] = *(const unsigned*)(xwb + (long)s * DD + c);
    }
    #pragma unroll
    for (int i = 0; i < 16; i++){
      ax[i & 7] += __uint_as_float(v[i] << 16) * w[i];
      ay[i & 7] += __uint_as_float(v[i] & 0xffff0000u) * w[i];
    }
  }
  int no = __builtin_amdgcn_readfirstlane(novf[0]);
  if (no > 0){
    no = no < OVF_CAP ? no : OVF_CAP;
    for (int k = 0; k < no; k++){
      int4 od = ovf[k];
      if (od.z == row){
        float w = rsqrtf((float)cnt[od.x] + 1.f);
        unsigned v = *(const unsigned*)(xwb + (long)od.x * DD + c);
        ax[0] += __uint_as_float(v << 16) * w;
        ay[0] += __uint_as_float(v & 0xffff0000u) * w;
      }
    }
  }
  float sax = ((ax[0]+ax[1])+(ax[2]+ax[3])) + ((ax[4]+ax[5])+(ax[6]+ax[7]));
  float say = ((ay[0]+ay[1])+(ay[2]+ay[3])) + ((ay[4]+ay[5])+(ay[6]+ay[7]));
  float dd = rsqrtf((float)deg + 1.f);
  unsigned sv = *(const unsigned*)(xwb + (long)row * DD + c);
  float sx = __uint_as_float(sv << 16), sy = __uint_as_float(sv & 0xffff0000u);
  float2 bb = *(const float2*)(b + c);
  float vx = sax * dd + sx * dd * dd + bb.x;
  float vy = say * dd + sy * dd * dd + bb.y;
  vx = vx > 0.f ? vx : expm1f(vx);
  vy = vy > 0.f ? vy : expm1f(vy);
  *(float2*)(out + (long)row * DD + c) = make_float2(vx, vy);
}

extern "C" void kernel_launch(void* const* d_in, const int* in_sizes, int n_in,
                              void* d_out, int out_size, void* d_ws, size_t ws_size,
                              hipStream_t stream) {
  const int*   edge   = (const int*)d_in[1];
  const float* px     = (const float*)d_in[2];
  const int*   pedge  = (const int*)d_in[3];
  const int*   unpool = (const int*)d_in[4];
  const float* W0 = (const float*)d_in[5]; const float* b0 = (const float*)d_in[6];
  const float* W1 = (const float*)d_in[7]; const float* b1 = (const float*)d_in[8];
  const float* W2 = (const float*)d_in[9]; const float* b2 = (const float*)d_in[10];
  const int n_full = in_sizes[0] / DD;
  const int E_full = in_sizes[1] / 2;
  const int n_pool = in_sizes[2] / DD;
  const int E_pool = in_sizes[3] / 2;
  float* out = (float*)d_out;

  // ---- workspace layout ----
  char* w = (char*)d_ws;
  size_t off = 0;
  auto alloc = [&](size_t bytes) -> void* {
    void* p = (void*)(w + off);
    off += (bytes + 255) / 256 * 256;
    return p;
  };
  // single zeroed span: [cnt_f | cnt_p | rk1 | novf3 | invm]  (invm: 0 = not pooled)
  int* cnt_f = (int*)alloc((size_t)n_full * 4);
  int* cnt_p = (int*)alloc((size_t)n_pool * 4);
  int* rk1   = (int*)alloc((size_t)n_full * 4);
  int* novf3 = (int*)alloc(12);                 // [0]=conv2, [1]=conv1, [2]=conv0
  int* invm  = (int*)alloc((size_t)n_full * 4);
  size_t zspan = (size_t)((char*)(invm + n_full) - (char*)cnt_f);
  int* rank_f = (int*)alloc((size_t)E_full * 4);
  int* rank_p = (int*)alloc((size_t)E_pool * 4);
  unsigned* ew2 = (unsigned*)alloc((size_t)n_full * CF * 4);
  unsigned* ew1 = (unsigned*)alloc((size_t)n_full * C1 * 4);
  unsigned* ew0 = (unsigned*)alloc((size_t)n_pool * CF * 4);
  int4* ovf2 = (int4*)alloc((size_t)OVF_CAP * 16);
  int4* ovf1 = (int4*)alloc((size_t)OVF_CAP * 16);
  int4* ovf0 = (int4*)alloc((size_t)OVF_CAP * 16);
  const size_t big = (size_t)n_full * DD * 4;
  float* bufA = (float*)alloc(big);
  float* bufB = (float*)alloc(big);

  const int* src_f = edge;          const int* dst_f = edge + E_full;
  const int* src_p = pedge;         const int* dst_p = pedge + E_pool;

  const int nF4 = E_full / 4, remF = E_full & 3;
  const int nP4 = E_pool / 4, remP = E_pool & 3;

  (void)hipMemsetAsync(cnt_f, 0, zspan, stream);
  k_count<<<cdiv((long)nF4 + remF + nP4 + remP + n_pool, 256), 256, 0, stream>>>(
      dst_f, nF4, E_full, cnt_f, rank_f,
      dst_p, nP4, E_pool, cnt_p, rank_p,
      unpool, invm, n_pool);
  k_fill<<<cdiv((long)nF4 + remF + nP4 + remP, 256), 256, 0, stream>>>(
      src_f, dst_f, nF4, E_full, rank_f, invm,
      ew2, ovf2, novf3 + 0,
      rk1, ew1, ovf1, novf3 + 1,
      src_p, dst_p, nP4, E_pool, rank_p,
      ew0, ovf0, novf3 + 2);

  float* xw0            = bufA;                   // pool rows fp32
  unsigned* h0p         = (unsigned*)bufB;        // pool rows packed hi/lo
  unsigned short* hw1b  = (unsigned short*)bufA;  // pool rows bf16 (xw0 dead)
  unsigned* y1p         = (unsigned*)bufB;        // full rows packed hi/lo (h0p dead after gemm1)
  unsigned short* xw2b  = (unsigned short*)bufA;  // full rows bf16 (hw1b dead after agg1)

  // conv0 (pooled graph)
  k_gemm_mfma<0,false><<<cdiv(n_pool,128),256,0,stream>>>(px, W0, xw0, n_pool);
  k_agg0<<<cdiv(n_pool,4),256,0,stream>>>(xw0, cnt_p, ew0, ovf0, novf3 + 2, b0, h0p, n_pool);

  // conv1 (full graph, compact pooled-src records)
  k_gemm_mfma<1,true><<<cdiv(n_pool,128),256,0,stream>>>(h0p, W1, hw1b, n_pool);
  k_agg1<<<cdiv(n_full,4),256,0,stream>>>(hw1b, invm, cnt_f, rk1, ew1, unpool,
                                          ovf1, novf3 + 1, b1, y1p, n_full);

  // conv2 (full graph, all edges)
  k_gemm_mfma<1,true><<<cdiv(n_full,128),256,0,stream>>>(y1p, W2, xw2b, n_full);
  k_agg2<<<cdiv(n_full,4),256,0,stream>>>(xw2b, cnt_f, ew2, ovf2, novf3 + 0, b2, out, n_full);
}

// Round 9
// 261.373 us; speedup vs baseline: 1.0627x; 1.0627x over previous
//
#include <hip/hip_runtime.h>
#include <math.h>

#define DD 128
#define CF 48          // bucket capacity/row: conv2 + conv0 (Poisson λ=12)
#define C1 16          // bucket capacity/row: conv1 compact (pooled-src only, λ≈3)
#define OVF_CAP 4096   // overflow side-list capacity (expected use: 0)

static inline int cdiv(long a, long b){ return (int)((a + b - 1) / b); }

typedef __attribute__((ext_vector_type(4))) float f32x4;
typedef __attribute__((ext_vector_type(8))) short bf16x8;
typedef __attribute__((ext_vector_type(4))) short sh4;

__device__ __forceinline__ unsigned short bf16_rn(float f){
  unsigned u = __float_as_uint(f);
  u += 0x7fffu + ((u >> 16) & 1u);
  return (unsigned short)(u >> 16);
}

// ---------- pass 1: degree count + rank capture, 4 edges/thread (4x atomic MLP) ----------
__global__ void k_count(const int* __restrict__ dst_f, int nF4, int Ef,
                        int* __restrict__ cnt_f, int* __restrict__ rank_f,
                        const int* __restrict__ dst_p, int nP4, int Ep,
                        int* __restrict__ cnt_p, int* __restrict__ rank_p,
                        const int* __restrict__ unpool, int* __restrict__ invm, int npool){
  int t = blockIdx.x * blockDim.x + threadIdx.x;
  if (t < nF4){
    int e = t * 4;
    int4 d = *(const int4*)(dst_f + e);
    int r0 = atomicAdd(&cnt_f[d.x], 1);
    int r1 = atomicAdd(&cnt_f[d.y], 1);
    int r2 = atomicAdd(&cnt_f[d.z], 1);
    int r3 = atomicAdd(&cnt_f[d.w], 1);
    *(int4*)(rank_f + e) = make_int4(r0, r1, r2, r3);
    return;
  }
  t -= nF4;
  int remF = Ef - nF4 * 4;
  if (t < remF){ int e = nF4 * 4 + t; rank_f[e] = atomicAdd(&cnt_f[dst_f[e]], 1); return; }
  t -= remF;
  if (t < nP4){
    int e = t * 4;
    int4 d = *(const int4*)(dst_p + e);
    int r0 = atomicAdd(&cnt_p[d.x], 1);
    int r1 = atomicAdd(&cnt_p[d.y], 1);
    int r2 = atomicAdd(&cnt_p[d.z], 1);
    int r3 = atomicAdd(&cnt_p[d.w], 1);
    *(int4*)(rank_p + e) = make_int4(r0, r1, r2, r3);
    return;
  }
  t -= nP4;
  int remP = Ep - nP4 * 4;
  if (t < remP){ int e = nP4 * 4 + t; rank_p[e] = atomicAdd(&cnt_p[dst_p[e]], 1); return; }
  t -= remP;
  if (t < npool) invm[unpool[t]] = t + 1;   // 0 = not pooled, else pr+1
}

// ---------- pass 2: bucket fill, 4 edges/thread, 4B packed records {id<<8 | deg} ----------
__global__ void k_fill(const int* __restrict__ src_f, const int* __restrict__ dst_f,
                       int nF4, int Ef,
                       const int* __restrict__ cnt_f, const int* __restrict__ rank_f,
                       const int* __restrict__ invm,
                       unsigned* __restrict__ ew2, int4* __restrict__ ovf2, int* __restrict__ novf2,
                       int* __restrict__ rk1, unsigned* __restrict__ ew1,
                       int4* __restrict__ ovf1, int* __restrict__ novf1,
                       const int* __restrict__ src_p, const int* __restrict__ dst_p,
                       int nP4, int Ep,
                       const int* __restrict__ cnt_p, const int* __restrict__ rank_p,
                       unsigned* __restrict__ ew0, int4* __restrict__ ovf0, int* __restrict__ novf0){
  int t = blockIdx.x * blockDim.x + threadIdx.x;
  if (t < nF4){
    int e = t * 4;
    int4 s4 = *(const int4*)(src_f + e);
    int4 d4 = *(const int4*)(dst_f + e);
    int4 r4 = *(const int4*)(rank_f + e);
    int sa[4] = {s4.x, s4.y, s4.z, s4.w};
    int da[4] = {d4.x, d4.y, d4.z, d4.w};
    int ra[4] = {r4.x, r4.y, r4.z, r4.w};
    int ca[4], pa[4];
    #pragma unroll
    for (int i = 0; i < 4; i++){
      int c = cnt_f[sa[i]]; ca[i] = c < 255 ? c : 255;
      pa[i] = invm[sa[i]];
    }
    #pragma unroll
    for (int i = 0; i < 4; i++){
      unsigned u = ((unsigned)sa[i] << 8) | (unsigned)ca[i];
      if (ra[i] < CF) ew2[(long)da[i] * CF + ra[i]] = u;
      else { int o = atomicAdd(novf2, 1); if (o < OVF_CAP) ovf2[o] = make_int4(sa[i], ca[i], da[i], 0); }
    }
    #pragma unroll
    for (int i = 0; i < 4; i++){
      if (pa[i] > 0){
        int pr = pa[i] - 1;
        int r1 = atomicAdd(&rk1[da[i]], 1);
        unsigned u1 = ((unsigned)pr << 8) | (unsigned)ca[i];
        if (r1 < C1) ew1[(long)da[i] * C1 + r1] = u1;
        else { int o = atomicAdd(novf1, 1); if (o < OVF_CAP) ovf1[o] = make_int4(pr, ca[i], da[i], 0); }
      }
    }
    return;
  }
  t -= nF4;
  int remF = Ef - nF4 * 4;
  if (t < remF){
    int e = nF4 * 4 + t;
    int s = src_f[e], d = dst_f[e], r = rank_f[e];
    int c = cnt_f[s]; c = c < 255 ? c : 255;
    unsigned u = ((unsigned)s << 8) | (unsigned)c;
    if (r < CF) ew2[(long)d * CF + r] = u;
    else { int o = atomicAdd(novf2, 1); if (o < OVF_CAP) ovf2[o] = make_int4(s, c, d, 0); }
    int pv = invm[s];
    if (pv > 0){
      int pr = pv - 1;
      int r1 = atomicAdd(&rk1[d], 1);
      unsigned u1 = ((unsigned)pr << 8) | (unsigned)c;
      if (r1 < C1) ew1[(long)d * C1 + r1] = u1;
      else { int o = atomicAdd(novf1, 1); if (o < OVF_CAP) ovf1[o] = make_int4(pr, c, d, 0); }
    }
    return;
  }
  t -= remF;
  if (t < nP4){
    int e = t * 4;
    int4 s4 = *(const int4*)(src_p + e);
    int4 d4 = *(const int4*)(dst_p + e);
    int4 r4 = *(const int4*)(rank_p + e);
    int sa[4] = {s4.x, s4.y, s4.z, s4.w};
    int da[4] = {d4.x, d4.y, d4.z, d4.w};
    int ra[4] = {r4.x, r4.y, r4.z, r4.w};
    int ca[4];
    #pragma unroll
    for (int i = 0; i < 4; i++){ int c = cnt_p[sa[i]]; ca[i] = c < 255 ? c : 255; }
    #pragma unroll
    for (int i = 0; i < 4; i++){
      unsigned u = ((unsigned)sa[i] << 8) | (unsigned)ca[i];
      if (ra[i] < CF) ew0[(long)da[i] * CF + ra[i]] = u;
      else { int o = atomicAdd(novf0, 1); if (o < OVF_CAP) ovf0[o] = make_int4(sa[i], ca[i], da[i], 0); }
    }
    return;
  }
  t -= nP4;
  int remP = Ep - nP4 * 4;
  if (t < remP){
    int e = nP4 * 4 + t;
    int s = src_p[e], d = dst_p[e], r = rank_p[e];
    int c = cnt_p[s]; c = c < 255 ? c : 255;
    unsigned u = ((unsigned)s << 8) | (unsigned)c;
    if (r < CF) ew0[(long)d * CF + r] = u;
    else { int o = atomicAdd(novf0, 1); if (o < OVF_CAP) ovf0[o] = make_int4(s, c, d, 0); }
  }
}

// ---------- MFMA GEMM: xw = A @ W, hi/lo bf16 split (fp32-grade accuracy)
// AMODE 0: A is fp32, split in-kernel. AMODE 1: A is packed ushort2{hi,lo} (uint per elem).
// 128 rows/block, 4 waves x 32 rows. W transposed+swizzled in LDS (hi/lo bf16, 64KB).
// D-layout (HW-verified): row = (lane>>4)*4 + reg, col = lane&15.
template <int AMODE, bool BF16OUT>
__global__ __launch_bounds__(256, 2) void k_gemm_mfma(const void* __restrict__ Ap,
                                                      const float* __restrict__ W,
                                                      void* __restrict__ Cout, int n){
  __shared__ unsigned short Wl[2][16384];   // [hi/lo][col-major bf16, XOR-swizzled 16B slots]
  const int t    = threadIdx.x;
  const int lane = t & 63;
  const int wv   = t >> 6;    // wave 0..3
  const int g    = lane >> 4; // k-group 0..3
  const int r    = lane & 15; // row-within-frag (A) / col-within-frag (B,D)

  // ---- stage W: read row-major fp32 coalesced, write transposed bf16 hi/lo ----
  // swizzle: byte = col*256 + ((k>>3) ^ (col&15))*16 + (k&7)*2
  #pragma unroll
  for (int i = 0; i < 4; i++){
    int item = t + i * 256;
    int kq = item >> 5;            // k = kq*4 + kk
    int c4 = item & 31;            // col = c4*4 + m
    const float* Wp = W + (long)kq * 512 + c4 * 4;
    float4 ww[4];
    #pragma unroll
    for (int kk = 0; kk < 4; kk++) ww[kk] = *(const float4*)(Wp + kk * 128);
    #pragma unroll
    for (int m = 0; m < 4; m++){
      int c = c4 * 4 + m;
      int boff = c * 256 + (((kq >> 1) ^ (c & 15)) * 16) + (kq & 1) * 8;
      sh4 hq, lq;
      #pragma unroll
      for (int kk = 0; kk < 4; kk++){
        float f = ((const float*)&ww[kk])[m];
        unsigned short hh = bf16_rn(f);
        float hf = __uint_as_float((unsigned)hh << 16);
        hq[kk] = (short)hh;
        lq[kk] = (short)bf16_rn(f - hf);
      }
      *(sh4*)((char*)(&Wl[0][0]) + boff) = hq;
      *(sh4*)((char*)(&Wl[1][0]) + boff) = lq;
    }
  }
  __syncthreads();

  const int rb = blockIdx.x * 128 + wv * 32;
  const int r0 = rb + r, r1 = rb + 16 + r;
  const bool v0 = r0 < n, v1 = r1 < n;

  f32x4 acc[2][8];
  #pragma unroll
  for (int i = 0; i < 2; i++)
    #pragma unroll
    for (int j = 0; j < 8; j++){ f32x4 z = {0.f,0.f,0.f,0.f}; acc[i][j] = z; }

  #pragma unroll
  for (int ks = 0; ks < 4; ks++){
    bf16x8 ah0, al0, ah1, al1;
    if (AMODE == 0){
      const float* pa0 = (const float*)Ap + (long)r0 * DD + g * 8;
      const float* pa1 = (const float*)Ap + (long)r1 * DD + g * 8;
      const float4 z4 = make_float4(0.f,0.f,0.f,0.f);
      float4 a00 = v0 ? *(const float4*)(pa0 + ks * 32)     : z4;
      float4 a01 = v0 ? *(const float4*)(pa0 + ks * 32 + 4) : z4;
      float4 a10 = v1 ? *(const float4*)(pa1 + ks * 32)     : z4;
      float4 a11 = v1 ? *(const float4*)(pa1 + ks * 32 + 4) : z4;
      float f0[8] = {a00.x,a00.y,a00.z,a00.w,a01.x,a01.y,a01.z,a01.w};
      float f1[8] = {a10.x,a10.y,a10.z,a10.w,a11.x,a11.y,a11.z,a11.w};
      #pragma unroll
      for (int i = 0; i < 8; i++){
        unsigned short hh = bf16_rn(f0[i]);
        ah0[i] = (short)hh;
        al0[i] = (short)bf16_rn(f0[i] - __uint_as_float((unsigned)hh << 16));
        unsigned short h1 = bf16_rn(f1[i]);
        ah1[i] = (short)h1;
        al1[i] = (short)bf16_rn(f1[i] - __uint_as_float((unsigned)h1 << 16));
      }
    } else {
      const unsigned* qa0 = (const unsigned*)Ap + (long)r0 * DD + g * 8;
      const unsigned* qa1 = (const unsigned*)Ap + (long)r1 * DD + g * 8;
      const uint4 z4 = make_uint4(0,0,0,0);
      uint4 u00 = v0 ? *(const uint4*)(qa0 + ks * 32)     : z4;
      uint4 u01 = v0 ? *(const uint4*)(qa0 + ks * 32 + 4) : z4;
      uint4 u10 = v1 ? *(const uint4*)(qa1 + ks * 32)     : z4;
      uint4 u11 = v1 ? *(const uint4*)(qa1 + ks * 32 + 4) : z4;
      unsigned uu0[8] = {u00.x,u00.y,u00.z,u00.w,u01.x,u01.y,u01.z,u01.w};
      unsigned uu1[8] = {u10.x,u10.y,u10.z,u10.w,u11.x,u11.y,u11.z,u11.w};
      #pragma unroll
      for (int i = 0; i < 8; i++){
        ah0[i] = (short)(uu0[i] & 0xffffu); al0[i] = (short)(uu0[i] >> 16);
        ah1[i] = (short)(uu1[i] & 0xffffu); al1[i] = (short)(uu1[i] >> 16);
      }
    }
    const int sb = ks * 4 + g;
    #pragma unroll
    for (int cf = 0; cf < 8; cf++){
      const int boff = (cf * 16 + r) * 256 + ((sb ^ r) * 16);
      bf16x8 wh = *(const bf16x8*)((const char*)(&Wl[0][0]) + boff);
      bf16x8 wl = *(const bf16x8*)((const char*)(&Wl[1][0]) + boff);
      acc[0][cf] = __builtin_amdgcn_mfma_f32_16x16x32_bf16(ah0, wh, acc[0][cf], 0, 0, 0);
      acc[1][cf] = __builtin_amdgcn_mfma_f32_16x16x32_bf16(ah1, wh, acc[1][cf], 0, 0, 0);
      acc[0][cf] = __builtin_amdgcn_mfma_f32_16x16x32_bf16(al0, wh, acc[0][cf], 0, 0, 0);
      acc[1][cf] = __builtin_amdgcn_mfma_f32_16x16x32_bf16(al1, wh, acc[1][cf], 0, 0, 0);
      acc[0][cf] = __builtin_amdgcn_mfma_f32_16x16x32_bf16(ah0, wl, acc[0][cf], 0, 0, 0);
      acc[1][cf] = __builtin_amdgcn_mfma_f32_16x16x32_bf16(ah1, wl, acc[1][cf], 0, 0, 0);
    }
  }

  #pragma unroll
  for (int rf = 0; rf < 2; rf++){
    #pragma unroll
    for (int cf = 0; cf < 8; cf++){
      #pragma unroll
      for (int e = 0; e < 4; e++){
        int row = rb + rf * 16 + g * 4 + e;
        if (row < n){
          float v = acc[rf][cf][e];
          if (BF16OUT)
            ((unsigned short*)Cout)[(long)row * DD + cf * 16 + r] = bf16_rn(v);
          else
            ((float*)Cout)[(long)row * DD + cf * 16 + r] = v;
        }
      }
    }
  }
}

// ---------- conv0 agg: pool graph, fp32 payload, predicated 16-batch ----------
__global__ __launch_bounds__(256) void k_agg0(const float* __restrict__ xw,
    const int* __restrict__ cnt, const unsigned* __restrict__ ew,
    const int4* __restrict__ ovf, const int* __restrict__ novf,
    const float* __restrict__ b, unsigned* __restrict__ outp, int n){
  int row = __builtin_amdgcn_readfirstlane(blockIdx.x * 4 + (threadIdx.x >> 6));
  if (row >= n) return;
  int c = (threadIdx.x & 63) * 2;
  int deg = __builtin_amdgcn_readfirstlane(cnt[row]);
  int m = deg < CF ? deg : CF;
  long base = (long)row * CF;
  float ax[8], ay[8];
  #pragma unroll
  for (int i = 0; i < 8; i++){ ax[i] = 0.f; ay[i] = 0.f; }
  for (int j0 = 0; j0 < m; j0 += 16){
    uint4 q0 = *(const uint4*)(ew + base + j0);
    uint4 q1 = *(const uint4*)(ew + base + j0 + 4);
    uint4 q2 = *(const uint4*)(ew + base + j0 + 8);
    uint4 q3 = *(const uint4*)(ew + base + j0 + 12);
    unsigned ua[16] = {q0.x,q0.y,q0.z,q0.w, q1.x,q1.y,q1.z,q1.w,
                       q2.x,q2.y,q2.z,q2.w, q3.x,q3.y,q3.z,q3.w};
    float2 v[16]; float w[16];
    #pragma unroll
    for (int i = 0; i < 16; i++){
      bool val = (j0 + i) < m;
      int s = val ? (int)(ua[i] >> 8) : row;      // invalid -> own row (hot line, w=0)
      w[i] = val ? rsqrtf((float)(ua[i] & 255u) + 1.f) : 0.f;
      v[i] = *(const float2*)(xw + (long)s * DD + c);
    }
    #pragma unroll
    for (int i = 0; i < 16; i++){
      ax[i & 7] += v[i].x * w[i];
      ay[i & 7] += v[i].y * w[i];
    }
  }
  int no = __builtin_amdgcn_readfirstlane(novf[0]);
  if (no > 0){
    no = no < OVF_CAP ? no : OVF_CAP;
    for (int k = 0; k < no; k++){
      int4 od = ovf[k];
      if (od.z == row){
        float w = rsqrtf((float)od.y + 1.f);
        float2 v = *(const float2*)(xw + (long)od.x * DD + c);
        ax[0] += v.x * w; ay[0] += v.y * w;
      }
    }
  }
  float sax = ((ax[0]+ax[1])+(ax[2]+ax[3])) + ((ax[4]+ax[5])+(ax[6]+ax[7]));
  float say = ((ay[0]+ay[1])+(ay[2]+ay[3])) + ((ay[4]+ay[5])+(ay[6]+ay[7]));
  float dd = rsqrtf((float)deg + 1.f);
  float2 sv = *(const float2*)(xw + (long)row * DD + c);
  float2 bb = *(const float2*)(b + c);
  float vx = sax * dd + sv.x * dd * dd + bb.x;
  float vy = say * dd + sv.y * dd * dd + bb.y;
  vx = vx > 0.f ? vx : expm1f(vx);
  vy = vy > 0.f ? vy : expm1f(vy);
  unsigned short hx = bf16_rn(vx);
  unsigned short lx = bf16_rn(vx - __uint_as_float((unsigned)hx << 16));
  unsigned short hy = bf16_rn(vy);
  unsigned short ly = bf16_rn(vy - __uint_as_float((unsigned)hy << 16));
  *(uint2*)(outp + (long)row * DD + c) =
      make_uint2((unsigned)hx | ((unsigned)lx << 16), (unsigned)hy | ((unsigned)ly << 16));
}

// ---------- conv1 agg: compact pooled-src records, single predicated 16-batch ----------
__global__ __launch_bounds__(256) void k_agg1(const unsigned short* __restrict__ hwb,
    const int* __restrict__ invm, const int* __restrict__ cnt_f,
    const int* __restrict__ rk1, const unsigned* __restrict__ ew,
    const int4* __restrict__ ovf, const int* __restrict__ novf,
    const float* __restrict__ b, unsigned* __restrict__ outp, int n){
  int row = __builtin_amdgcn_readfirstlane(blockIdx.x * 4 + (threadIdx.x >> 6));
  if (row >= n) return;
  int c = (threadIdx.x & 63) * 2;
  int m1 = __builtin_amdgcn_readfirstlane(rk1[row]);
  if (m1 > C1) m1 = C1;
  int deg = __builtin_amdgcn_readfirstlane(cnt_f[row]);
  long base = (long)row * C1;
  int pv = __builtin_amdgcn_readfirstlane(invm[row]);
  float ax[8], ay[8];
  #pragma unroll
  for (int i = 0; i < 8; i++){ ax[i] = 0.f; ay[i] = 0.f; }
  if (m1 > 0){
    uint4 q0 = *(const uint4*)(ew + base);
    uint4 q1 = *(const uint4*)(ew + base + 4);
    uint4 q2 = *(const uint4*)(ew + base + 8);
    uint4 q3 = *(const uint4*)(ew + base + 12);
    unsigned ua[16] = {q0.x,q0.y,q0.z,q0.w, q1.x,q1.y,q1.z,q1.w,
                       q2.x,q2.y,q2.z,q2.w, q3.x,q3.y,q3.z,q3.w};
    unsigned v[16]; float w[16];
    #pragma unroll
    for (int i = 0; i < 16; i++){
      bool val = i < m1;
      int pr = val ? (int)(ua[i] >> 8) : 0;       // row 0 of hwb: valid data, w=0
      w[i] = val ? rsqrtf((float)(ua[i] & 255u) + 1.f) : 0.f;
      v[i] = *(const unsigned*)(hwb + (long)pr * DD + c);
    }
    #pragma unroll
    for (int i = 0; i < 16; i++){
      ax[i & 7] += __uint_as_float(v[i] << 16) * w[i];
      ay[i & 7] += __uint_as_float(v[i] & 0xffff0000u) * w[i];
    }
  }
  int no = __builtin_amdgcn_readfirstlane(novf[0]);
  if (no > 0){
    no = no < OVF_CAP ? no : OVF_CAP;
    for (int k = 0; k < no; k++){
      int4 od = ovf[k];
      if (od.z == row){
        float w = rsqrtf((float)od.y + 1.f);
        unsigned v = *(const unsigned*)(hwb + (long)od.x * DD + c);
        ax[0] += __uint_as_float(v << 16) * w;
        ay[0] += __uint_as_float(v & 0xffff0000u) * w;
      }
    }
  }
  float sax = ((ax[0]+ax[1])+(ax[2]+ax[3])) + ((ax[4]+ax[5])+(ax[6]+ax[7]));
  float say = ((ay[0]+ay[1])+(ay[2]+ay[3])) + ((ay[4]+ay[5])+(ay[6]+ay[7]));
  float dd = rsqrtf((float)deg + 1.f);
  float sx = 0.f, sy = 0.f;
  if (pv > 0){
    unsigned sv = *(const unsigned*)(hwb + (long)(pv - 1) * DD + c);
    sx = __uint_as_float(sv << 16); sy = __uint_as_float(sv & 0xffff0000u);
  }
  float2 bb = *(const float2*)(b + c);
  float vx = sax * dd + sx * dd * dd + bb.x;
  float vy = say * dd + sy * dd * dd + bb.y;
  vx = vx > 0.f ? vx : expm1f(vx);
  vy = vy > 0.f ? vy : expm1f(vy);
  unsigned short hx = bf16_rn(vx);
  unsigned short lx = bf16_rn(vx - __uint_as_float((unsigned)hx << 16));
  unsigned short hy = bf16_rn(vy);
  unsigned short ly = bf16_rn(vy - __uint_as_float((unsigned)hy << 16));
  *(uint2*)(outp + (long)row * DD + c) =
      make_uint2((unsigned)hx | ((unsigned)lx << 16), (unsigned)hy | ((unsigned)ly << 16));
}

// ---------- conv2 agg: full graph, predicated 16-batch, bf16 payload, fp32 out ----------
__global__ __launch_bounds__(256) void k_agg2(const unsigned short* __restrict__ xwb,
    const int* __restrict__ cnt, const unsigned* __restrict__ ew,
    const int4* __restrict__ ovf, const int* __restrict__ novf,
    const float* __restrict__ b, float* __restrict__ out, int n){
  int row = __builtin_amdgcn_readfirstlane(blockIdx.x * 4 + (threadIdx.x >> 6));
  if (row >= n) return;
  int c = (threadIdx.x & 63) * 2;
  int deg = __builtin_amdgcn_readfirstlane(cnt[row]);
  int m = deg < CF ? deg : CF;
  long base = (long)row * CF;
  float ax[8], ay[8];
  #pragma unroll
  for (int i = 0; i < 8; i++){ ax[i] = 0.f; ay[i] = 0.f; }
  for (int j0 = 0; j0 < m; j0 += 16){
    uint4 q0 = *(const uint4*)(ew + base + j0);
    uint4 q1 = *(const uint4*)(ew + base + j0 + 4);
    uint4 q2 = *(const uint4*)(ew + base + j0 + 8);
    uint4 q3 = *(const uint4*)(ew + base + j0 + 12);
    unsigned ua[16] = {q0.x,q0.y,q0.z,q0.w, q1.x,q1.y,q1.z,q1.w,
                       q2.x,q2.y,q2.z,q2.w, q3.x,q3.y,q3.z,q3.w};
    unsigned v[16]; float w[16];
    #pragma unroll
    for (int i = 0; i < 16; i++){
      bool val = (j0 + i) < m;
      int s = val ? (int)(ua[i] >> 8) : row;      // invalid -> own row (hot line, w=0)
      w[i] = val ? rsqrtf((float)(ua[i] & 255u) + 1.f) : 0.f;
      v[i] = *(const unsigned*)(xwb + (long)s * DD + c);
    }
    #pragma unroll
    for (int i = 0; i < 16; i++){
      ax[i & 7] += __uint_as_float(v[i] << 16) * w[i];
      ay[i & 7] += __uint_as_float(v[i] & 0xffff0000u) * w[i];
    }
  }
  int no = __builtin_amdgcn_readfirstlane(novf[0]);
  if (no > 0){
    no = no < OVF_CAP ? no : OVF_CAP;
    for (int k = 0; k < no; k++){
      int4 od = ovf[k];
      if (od.z == row){
        float w = rsqrtf((float)od.y + 1.f);
        unsigned v = *(const unsigned*)(xwb + (long)od.x * DD + c);
        ax[0] += __uint_as_float(v << 16) * w;
        ay[0] += __uint_as_float(v & 0xffff0000u) * w;
      }
    }
  }
  float sax = ((ax[0]+ax[1])+(ax[2]+ax[3])) + ((ax[4]+ax[5])+(ax[6]+ax[7]));
  float say = ((ay[0]+ay[1])+(ay[2]+ay[3])) + ((ay[4]+ay[5])+(ay[6]+ay[7]));
  float dd = rsqrtf((float)deg + 1.f);
  unsigned sv = *(const unsigned*)(xwb + (long)row * DD + c);
  float sx = __uint_as_float(sv << 16), sy = __uint_as_float(sv & 0xffff0000u);
  float2 bb = *(const float2*)(b + c);
  float vx = sax * dd + sx * dd * dd + bb.x;
  float vy = say * dd + sy * dd * dd + bb.y;
  vx = vx > 0.f ? vx : expm1f(vx);
  vy = vy > 0.f ? vy : expm1f(vy);
  *(float2*)(out + (long)row * DD + c) = make_float2(vx, vy);
}

extern "C" void kernel_launch(void* const* d_in, const int* in_sizes, int n_in,
                              void* d_out, int out_size, void* d_ws, size_t ws_size,
                              hipStream_t stream) {
  const int*   edge   = (const int*)d_in[1];
  const float* px     = (const float*)d_in[2];
  const int*   pedge  = (const int*)d_in[3];
  const int*   unpool = (const int*)d_in[4];
  const float* W0 = (const float*)d_in[5]; const float* b0 = (const float*)d_in[6];
  const float* W1 = (const float*)d_in[7]; const float* b1 = (const float*)d_in[8];
  const float* W2 = (const float*)d_in[9]; const float* b2 = (const float*)d_in[10];
  const int n_full = in_sizes[0] / DD;
  const int E_full = in_sizes[1] / 2;
  const int n_pool = in_sizes[2] / DD;
  const int E_pool = in_sizes[3] / 2;
  float* out = (float*)d_out;

  // ---- workspace layout ----
  char* w = (char*)d_ws;
  size_t off = 0;
  auto alloc = [&](size_t bytes) -> void* {
    void* p = (void*)(w + off);
    off += (bytes + 255) / 256 * 256;
    return p;
  };
  // single zeroed span: [cnt_f | cnt_p | rk1 | novf3 | invm]  (invm: 0 = not pooled)
  int* cnt_f = (int*)alloc((size_t)n_full * 4);
  int* cnt_p = (int*)alloc((size_t)n_pool * 4);
  int* rk1   = (int*)alloc((size_t)n_full * 4);
  int* novf3 = (int*)alloc(12);                 // [0]=conv2, [1]=conv1, [2]=conv0
  int* invm  = (int*)alloc((size_t)n_full * 4);
  size_t zspan = (size_t)((char*)(invm + n_full) - (char*)cnt_f);
  int* rank_f = (int*)alloc((size_t)E_full * 4);
  int* rank_p = (int*)alloc((size_t)E_pool * 4);
  unsigned* ew2 = (unsigned*)alloc((size_t)n_full * CF * 4);
  unsigned* ew1 = (unsigned*)alloc((size_t)n_full * C1 * 4);
  unsigned* ew0 = (unsigned*)alloc((size_t)n_pool * CF * 4);
  int4* ovf2 = (int4*)alloc((size_t)OVF_CAP * 16);
  int4* ovf1 = (int4*)alloc((size_t)OVF_CAP * 16);
  int4* ovf0 = (int4*)alloc((size_t)OVF_CAP * 16);
  const size_t big = (size_t)n_full * DD * 4;
  float* bufA = (float*)alloc(big);
  float* bufB = (float*)alloc(big);

  const int* src_f = edge;          const int* dst_f = edge + E_full;
  const int* src_p = pedge;         const int* dst_p = pedge + E_pool;

  const int nF4 = E_full / 4, remF = E_full & 3;
  const int nP4 = E_pool / 4, remP = E_pool & 3;

  (void)hipMemsetAsync(cnt_f, 0, zspan, stream);
  k_count<<<cdiv((long)nF4 + remF + nP4 + remP + n_pool, 256), 256, 0, stream>>>(
      dst_f, nF4, E_full, cnt_f, rank_f,
      dst_p, nP4, E_pool, cnt_p, rank_p,
      unpool, invm, n_pool);
  k_fill<<<cdiv((long)nF4 + remF + nP4 + remP, 256), 256, 0, stream>>>(
      src_f, dst_f, nF4, E_full, cnt_f, rank_f, invm,
      ew2, ovf2, novf3 + 0,
      rk1, ew1, ovf1, novf3 + 1,
      src_p, dst_p, nP4, E_pool, cnt_p, rank_p,
      ew0, ovf0, novf3 + 2);

  float* xw0            = bufA;                   // pool rows fp32
  unsigned* h0p         = (unsigned*)bufB;        // pool rows packed hi/lo
  unsigned short* hw1b  = (unsigned short*)bufA;  // pool rows bf16 (xw0 dead)
  unsigned* y1p         = (unsigned*)bufB;        // full rows packed hi/lo (h0p dead after gemm1)
  unsigned short* xw2b  = (unsigned short*)bufA;  // full rows bf16 (hw1b dead after agg1)

  // conv0 (pooled graph)
  k_gemm_mfma<0,false><<<cdiv(n_pool,128),256,0,stream>>>(px, W0, xw0, n_pool);
  k_agg0<<<cdiv(n_pool,4),256,0,stream>>>(xw0, cnt_p, ew0, ovf0, novf3 + 2, b0, h0p, n_pool);

  // conv1 (full graph, compact pooled-src records)
  k_gemm_mfma<1,true><<<cdiv(n_pool,128),256,0,stream>>>(h0p, W1, hw1b, n_pool);
  k_agg1<<<cdiv(n_full,4),256,0,stream>>>(hw1b, invm, cnt_f, rk1, ew1, ovf1, novf3 + 1, b1, y1p, n_full);

  // conv2 (full graph, all edges)
  k_gemm_mfma<1,true><<<cdiv(n_full,128),256,0,stream>>>(y1p, W2, xw2b, n_full);
  k_agg2<<<cdiv(n_full,4),256,0,stream>>>(xw2b, cnt_f, ew2, ovf2, novf3 + 0, b2, out, n_full);
}